// Round 1
// baseline (11187.867 us; speedup 1.0000x reference)
//
#include <hip/hip_runtime.h>
#include <math.h>

#define N_USERS 50000
#define N_ITEMS 50000
#define N_NODES 100000
#define DIM 64
#define BATCH 2048
#define SLOTS 4096

// ---------------- helpers ----------------

__device__ __forceinline__ float wave_reduce_sum(float v) {
#pragma unroll
  for (int off = 32; off > 0; off >>= 1)
    v += __shfl_xor(v, off, 64);
  return v;
}

__device__ __forceinline__ const float* ego_row(const float* ue, const float* ie, int n) {
  return (n < N_USERS) ? (ue + (size_t)n * DIM) : (ie + (size_t)(n - N_USERS) * DIM);
}

// ---------------- kernels ----------------

// map[node] = slot for batch nodes (duplicates: arbitrary winner, consistent afterwards)
__global__ void build_map_kernel(const int* __restrict__ nu, const int* __restrict__ ni,
                                 int* __restrict__ map) {
  int s = blockIdx.x * blockDim.x + threadIdx.x;
  if (s >= SLOTS) return;
  int n = (s < BATCH) ? nu[s] : (N_USERS + ni[s - BATCH]);
  map[n] = s;
}

// graph1 SpMM, but only rows that are batch nodes (via map). One wave per edge.
__global__ void spmm_flagged_kernel(const int* __restrict__ rows, const int* __restrict__ cols,
                                    const float* __restrict__ vals, const float* __restrict__ ue,
                                    const float* __restrict__ ie, const int* __restrict__ map,
                                    float* __restrict__ z1acc, int nE) {
  int e = blockIdx.x * 4 + (threadIdx.x >> 6);
  if (e >= nE) return;
  int r = rows[e];
  int s = map[r];
  if (s < 0) return;  // wave-uniform branch
  int lane = threadIdx.x & 63;
  int c = cols[e];
  float v = vals[e];
  const float* x = ego_row(ue, ie, c);
  unsafeAtomicAdd(&z1acc[(size_t)s * DIM + lane], v * x[lane]);
}

// graph2 full SpMM. One wave per edge, 64 fp32 atomics.
__global__ void spmm_full_kernel(const int* __restrict__ rows, const int* __restrict__ cols,
                                 const float* __restrict__ vals, const float* __restrict__ ue,
                                 const float* __restrict__ ie, float* __restrict__ acc2, int nE) {
  int e = blockIdx.x * 4 + (threadIdx.x >> 6);
  if (e >= nE) return;
  int lane = threadIdx.x & 63;
  int r = rows[e];
  int c = cols[e];
  float v = vals[e];
  const float* x = ego_row(ue, ie, c);
  unsafeAtomicAdd(&acc2[(size_t)r * DIM + lane], v * x[lane]);
}

// acc2 <- l2norm(0.5*(ego + acc2)) in place. One wave per node.
__global__ void normalize2_kernel(const float* __restrict__ ue, const float* __restrict__ ie,
                                  float* __restrict__ acc2) {
  int n = blockIdx.x * 4 + (threadIdx.x >> 6);
  if (n >= N_NODES) return;
  int lane = threadIdx.x & 63;
  const float* e = ego_row(ue, ie, n);
  float v = 0.5f * (e[lane] + acc2[(size_t)n * DIM + lane]);
  float ss = wave_reduce_sum(v * v);
  float inv = 1.0f / fmaxf(sqrtf(ss), 1e-12f);
  acc2[(size_t)n * DIM + lane] = v * inv;
}

// z1n[slot] = l2norm(0.5*(ego[n] + z1acc[map[n]])); also the pos term:
// out -= dot(z1, z2)  (z2 = normalized zall row n; factor SSL_REG*1/temp = 1 folded)
__global__ void gather1_kernel(const float* __restrict__ ue, const float* __restrict__ ie,
                               const int* __restrict__ nu, const int* __restrict__ ni,
                               const int* __restrict__ map, const float* __restrict__ z1acc,
                               const float* __restrict__ zall, float* __restrict__ z1n,
                               float* __restrict__ out) {
  int s = blockIdx.x * 4 + (threadIdx.x >> 6);
  if (s >= SLOTS) return;
  int lane = threadIdx.x & 63;
  int n = (s < BATCH) ? nu[s] : (N_USERS + ni[s - BATCH]);
  int fs = map[n];
  const float* e = ego_row(ue, ie, n);
  float v = 0.5f * (e[lane] + z1acc[(size_t)fs * DIM + lane]);
  float ss = wave_reduce_sum(v * v);
  float z = v / fmaxf(sqrtf(ss), 1e-12f);
  z1n[(size_t)s * DIM + lane] = z;
  float dp = wave_reduce_sum(z * zall[(size_t)n * DIM + lane]);
  if (lane == 0) atomicAdd(out, -dp);
}

// ttl[i] = sum_j exp(2*dot(z1n[i], zall[j])) over the 50000-row side of i.
// Block: 32 batch rows (tile in LDS) x 12500-j strip; 4 j-strips per row-block.
__global__ __launch_bounds__(256) void ttl_kernel(const float* __restrict__ z1n,
                                                  const float* __restrict__ zall,
                                                  float* __restrict__ ttl) {
  int rb = blockIdx.x >> 2;
  int h = blockIdx.x & 3;
  int r0 = rb * 32;
  int side = r0 >> 11;  // rows 0..2047 users, 2048..4095 items
  int tid = threadIdx.x;

  __shared__ float4 z1s4[512];  // 32 rows x 64 floats
  float* z1s = (float*)z1s4;
  const float4* src = (const float4*)(z1n + (size_t)r0 * DIM);
  z1s4[tid] = src[tid];
  z1s4[tid + 256] = src[tid + 256];
  __syncthreads();

  const float* zbase = zall + (size_t)side * N_USERS * DIM;
  int jlo = h * 12500, jhi = jlo + 12500;

  float acc[32];
#pragma unroll
  for (int r = 0; r < 32; r++) acc[r] = 0.f;

  for (int j = jlo + tid; j < jhi; j += 512) {
    int j2 = j + 256;
    bool has2 = (j2 < jhi);
    const float4* za = (const float4*)(zbase + (size_t)j * DIM);
    const float4* zb = (const float4*)(zbase + (size_t)(has2 ? j2 : j) * DIM);
    float4 A[16], B[16];
#pragma unroll
    for (int k = 0; k < 16; k++) { A[k] = za[k]; B[k] = zb[k]; }
#pragma unroll
    for (int r = 0; r < 32; r++) {
      const float4* zr = (const float4*)(z1s + r * DIM);
      float da = 0.f, db = 0.f;
#pragma unroll
      for (int k = 0; k < 16; k++) {
        float4 c = zr[k];
        da += A[k].x * c.x + A[k].y * c.y + A[k].z * c.z + A[k].w * c.w;
        db += B[k].x * c.x + B[k].y * c.y + B[k].z * c.z + B[k].w * c.w;
      }
      acc[r] += __expf(2.f * da) + (has2 ? __expf(2.f * db) : 0.f);
    }
  }

  __shared__ float part[4][32];
  int wave = tid >> 6, lane = tid & 63;
#pragma unroll
  for (int r = 0; r < 32; r++) {
    float v = wave_reduce_sum(acc[r]);
    if (lane == 0) part[wave][r] = v;
  }
  __syncthreads();
  if (tid < 32) {
    float s = part[0][tid] + part[1][tid] + part[2][tid] + part[3][tid];
    atomicAdd(&ttl[r0 + tid], s);
  }
}

// out += 0.5 * sum_i log(ttl[i])
__global__ void final_kernel(const float* __restrict__ ttl, float* __restrict__ out) {
  int t = blockIdx.x * blockDim.x + threadIdx.x;
  float v = (t < SLOTS) ? 0.5f * logf(ttl[t]) : 0.f;
  v = wave_reduce_sum(v);
  if ((threadIdx.x & 63) == 0) atomicAdd(out, v);
}

// ---------------- launch ----------------

extern "C" void kernel_launch(void* const* d_in, const int* in_sizes, int n_in,
                              void* d_out, int out_size, void* d_ws, size_t ws_size,
                              hipStream_t stream) {
  const float* ue = (const float*)d_in[0];
  const float* ie = (const float*)d_in[1];
  const int* rows1 = (const int*)d_in[2];
  const int* cols1 = (const int*)d_in[3];
  const float* vals1 = (const float*)d_in[4];
  const int* rows2 = (const int*)d_in[5];
  const int* cols2 = (const int*)d_in[6];
  const float* vals2 = (const float*)d_in[7];
  const int* nu = (const int*)d_in[8];
  const int* ni = (const int*)d_in[9];
  int nE1 = in_sizes[2], nE2 = in_sizes[5];

  // workspace layout (all offsets 256B-aligned), total ~28.1 MB
  char* ws = (char*)d_ws;
  int* map = (int*)(ws + 0);               // 100000 * 4   = 400000 B
  float* z1acc = (float*)(ws + 409600);    // 4096*64*4    = 1048576 B
  float* z1n = (float*)(ws + 1458176);     // 4096*64*4    = 1048576 B
  float* ttl = (float*)(ws + 2506752);     // 4096*4       = 16384 B
  float* acc2 = (float*)(ws + 2523136);    // 100000*64*4  = 25600000 B
  float* out = (float*)d_out;

  hipMemsetAsync(map, 0xFF, 400000, stream);     // -1
  hipMemsetAsync(z1acc, 0, 1048576, stream);
  hipMemsetAsync(ttl, 0, 16384, stream);
  hipMemsetAsync(acc2, 0, 25600000, stream);
  hipMemsetAsync(out, 0, sizeof(float), stream);

  build_map_kernel<<<16, 256, 0, stream>>>(nu, ni, map);
  spmm_flagged_kernel<<<(nE1 + 3) / 4, 256, 0, stream>>>(rows1, cols1, vals1, ue, ie, map, z1acc, nE1);
  spmm_full_kernel<<<(nE2 + 3) / 4, 256, 0, stream>>>(rows2, cols2, vals2, ue, ie, acc2, nE2);
  normalize2_kernel<<<(N_NODES + 3) / 4, 256, 0, stream>>>(ue, ie, acc2);
  gather1_kernel<<<SLOTS / 4, 256, 0, stream>>>(ue, ie, nu, ni, map, z1acc, acc2, z1n, out);
  ttl_kernel<<<512, 256, 0, stream>>>(z1n, acc2, ttl);
  final_kernel<<<16, 256, 0, stream>>>(ttl, out);
}

// Round 2
// 1036.574 us; speedup vs baseline: 10.7931x; 10.7931x over previous
//
#include <hip/hip_runtime.h>
#include <hip/hip_bf16.h>
#include <math.h>

#define N_USERS 50000
#define N_ITEMS 50000
#define N_NODES 100000
#define DIM 64
#define BATCH 2048
#define SLOTS 4096

using frag_ab = __attribute__((ext_vector_type(8))) short;  // 8 bf16
using frag_cd = __attribute__((ext_vector_type(4))) float;  // 4 fp32

// ---------------- helpers ----------------

__device__ __forceinline__ float wave_reduce_sum(float v) {
#pragma unroll
  for (int off = 32; off > 0; off >>= 1)
    v += __shfl_xor(v, off, 64);
  return v;
}

__device__ __forceinline__ const float* ego_row(const float* ue, const float* ie, int n) {
  return (n < N_USERS) ? (ue + (size_t)n * DIM) : (ie + (size_t)(n - N_USERS) * DIM);
}

__device__ __forceinline__ ushort f2bf(float x) {
  __hip_bfloat16 h = __float2bfloat16(x);
  return *(ushort*)&h;
}

// ---------------- kernels ----------------

__global__ void build_map_kernel(const int* __restrict__ nu, const int* __restrict__ ni,
                                 int* __restrict__ map) {
  int s = blockIdx.x * blockDim.x + threadIdx.x;
  if (s >= SLOTS) return;
  int n = (s < BATCH) ? nu[s] : (N_USERS + ni[s - BATCH]);
  map[n] = s;
}

// graph1 SpMM, only rows that are batch nodes (via map). One wave per edge.
__global__ void spmm_flagged_kernel(const int* __restrict__ rows, const int* __restrict__ cols,
                                    const float* __restrict__ vals, const float* __restrict__ ue,
                                    const float* __restrict__ ie, const int* __restrict__ map,
                                    float* __restrict__ z1acc, int nE) {
  int e = blockIdx.x * 4 + (threadIdx.x >> 6);
  if (e >= nE) return;
  int r = rows[e];
  int s = map[r];
  if (s < 0) return;  // wave-uniform branch
  int lane = threadIdx.x & 63;
  int c = cols[e];
  float v = vals[e];
  const float* x = ego_row(ue, ie, c);
  unsafeAtomicAdd(&z1acc[(size_t)s * DIM + lane], v * x[lane]);
}

// graph2 full SpMM. One wave per edge, 64 fp32 atomics.
__global__ void spmm_full_kernel(const int* __restrict__ rows, const int* __restrict__ cols,
                                 const float* __restrict__ vals, const float* __restrict__ ue,
                                 const float* __restrict__ ie, float* __restrict__ acc2, int nE) {
  int e = blockIdx.x * 4 + (threadIdx.x >> 6);
  if (e >= nE) return;
  int lane = threadIdx.x & 63;
  int r = rows[e];
  int c = cols[e];
  float v = vals[e];
  const float* x = ego_row(ue, ie, c);
  unsafeAtomicAdd(&acc2[(size_t)r * DIM + lane], v * x[lane]);
}

// acc2 <- l2norm(0.5*(ego + acc2)) in place; also write bf16 copy. One wave per node.
__global__ void normalize2_kernel(const float* __restrict__ ue, const float* __restrict__ ie,
                                  float* __restrict__ acc2, ushort* __restrict__ zallb) {
  int n = blockIdx.x * 4 + (threadIdx.x >> 6);
  if (n >= N_NODES) return;
  int lane = threadIdx.x & 63;
  const float* e = ego_row(ue, ie, n);
  float v = 0.5f * (e[lane] + acc2[(size_t)n * DIM + lane]);
  float ss = wave_reduce_sum(v * v);
  float inv = 1.0f / fmaxf(sqrtf(ss), 1e-12f);
  float z = v * inv;
  acc2[(size_t)n * DIM + lane] = z;
  zallb[(size_t)n * DIM + lane] = f2bf(z);
}

// z1 normalize (fp32 math, bf16 output) + pos term: out -= dot(z1, z2).
__global__ void gather1_kernel(const float* __restrict__ ue, const float* __restrict__ ie,
                               const int* __restrict__ nu, const int* __restrict__ ni,
                               const int* __restrict__ map, const float* __restrict__ z1acc,
                               const float* __restrict__ zall, ushort* __restrict__ z1b,
                               float* __restrict__ out) {
  int s = blockIdx.x * 4 + (threadIdx.x >> 6);
  if (s >= SLOTS) return;
  int lane = threadIdx.x & 63;
  int n = (s < BATCH) ? nu[s] : (N_USERS + ni[s - BATCH]);
  int fs = map[n];
  const float* e = ego_row(ue, ie, n);
  float v = 0.5f * (e[lane] + z1acc[(size_t)fs * DIM + lane]);
  float ss = wave_reduce_sum(v * v);
  float z = v / fmaxf(sqrtf(ss), 1e-12f);
  z1b[(size_t)s * DIM + lane] = f2bf(z);
  float dp = wave_reduce_sum(z * zall[(size_t)n * DIM + lane]);
  if (lane == 0) atomicAdd(out, -dp);
}

// ttl[i] = sum_j exp(2*dot(z1[i], zall_side[j])) via bf16 MFMA.
// Wave tile: 16 batch rows x 16 j-cols per MFMA-pair (K=64 = 2 mfma_16x16x32).
// Block = 4 waves = 64 rows, sweeping one j-strip of 125 chunks (2000 j).
// Grid = 64 row-blocks x 25 strips. A/B frags share the lane layout
// (row=lane&15, k=(lane>>4)*8+j) -> B loads straight from global: 16B/lane
// over 16 rows = 16 fully-used 64B lines per instruction.
#define STRIPS 25
#define JCHUNKS 125
__global__ __launch_bounds__(256) void ttl_mfma_kernel(const ushort* __restrict__ z1b,
                                                       const ushort* __restrict__ zallb,
                                                       float* __restrict__ ttl) {
  int rb = blockIdx.x / STRIPS;
  int strip = blockIdx.x % STRIPS;
  int wave = threadIdx.x >> 6;
  int lane = threadIdx.x & 63;
  int r0 = rb * 64 + wave * 16;
  int side = r0 >> 11;  // rows 0..2047 users, 2048..4095 items
  const ushort* zs = zallb + (size_t)side * N_USERS * DIM;

  int m = lane & 15, q = lane >> 4;
  const ushort* arow = z1b + (size_t)(r0 + m) * DIM + q * 8;
  frag_ab a0 = *(const frag_ab*)arow;
  frag_ab a1 = *(const frag_ab*)(arow + 32);

  float racc[4] = {0.f, 0.f, 0.f, 0.f};
  int j0 = strip * JCHUNKS * 16;
  const ushort* brow = zs + (size_t)(j0 + m) * DIM + q * 8;

  frag_ab b0 = *(const frag_ab*)brow;
  frag_ab b1 = *(const frag_ab*)(brow + 32);
  for (int c = 0; c < JCHUNKS; c++) {
    // prefetch next chunk's B frags (register double-buffer)
    frag_ab nb0, nb1;
    if (c + 1 < JCHUNKS) {
      const ushort* nbrow = brow + 16 * DIM;
      nb0 = *(const frag_ab*)nbrow;
      nb1 = *(const frag_ab*)(nbrow + 32);
    }
    frag_cd acc = {};
    acc = __builtin_amdgcn_mfma_f32_16x16x32_bf16(a0, b0, acc, 0, 0, 0);
    acc = __builtin_amdgcn_mfma_f32_16x16x32_bf16(a1, b1, acc, 0, 0, 0);
    racc[0] += __expf(2.f * acc[0]);
    racc[1] += __expf(2.f * acc[1]);
    racc[2] += __expf(2.f * acc[2]);
    racc[3] += __expf(2.f * acc[3]);
    b0 = nb0;
    b1 = nb1;
    brow += 16 * DIM;
  }

  // C layout: col=lane&15, row=(lane>>4)*4+reg. Sum over cols = reduce across
  // the 16 lanes sharing q.
#pragma unroll
  for (int r = 0; r < 4; r++) {
    float v = racc[r];
    v += __shfl_xor(v, 1, 64);
    v += __shfl_xor(v, 2, 64);
    v += __shfl_xor(v, 4, 64);
    v += __shfl_xor(v, 8, 64);
    if (m == 0) atomicAdd(&ttl[r0 + q * 4 + r], v);
  }
}

// out += 0.5 * sum_i log(ttl[i])
__global__ void final_kernel(const float* __restrict__ ttl, float* __restrict__ out) {
  int t = blockIdx.x * blockDim.x + threadIdx.x;
  float v = (t < SLOTS) ? 0.5f * logf(ttl[t]) : 0.f;
  v = wave_reduce_sum(v);
  if ((threadIdx.x & 63) == 0) atomicAdd(out, v);
}

// ---------------- launch ----------------

extern "C" void kernel_launch(void* const* d_in, const int* in_sizes, int n_in,
                              void* d_out, int out_size, void* d_ws, size_t ws_size,
                              hipStream_t stream) {
  const float* ue = (const float*)d_in[0];
  const float* ie = (const float*)d_in[1];
  const int* rows1 = (const int*)d_in[2];
  const int* cols1 = (const int*)d_in[3];
  const float* vals1 = (const float*)d_in[4];
  const int* rows2 = (const int*)d_in[5];
  const int* cols2 = (const int*)d_in[6];
  const float* vals2 = (const float*)d_in[7];
  const int* nu = (const int*)d_in[8];
  const int* ni = (const int*)d_in[9];
  int nE1 = in_sizes[2], nE2 = in_sizes[5];

  // workspace layout (256B-aligned), total ~40.4 MB
  char* ws = (char*)d_ws;
  int* map = (int*)(ws + 0);                   // 100000*4    = 400000 B
  float* z1acc = (float*)(ws + 409600);        // 4096*64*4   = 1048576 B
  float* ttl = (float*)(ws + 1458176);         // 4096*4      = 16384 B
  float* acc2 = (float*)(ws + 1474560);        // 100000*64*4 = 25600000 B
  ushort* zallb = (ushort*)(ws + 27074560);    // 100000*64*2 = 12800000 B
  ushort* z1b = (ushort*)(ws + 39874560);      // 4096*64*2   = 524288 B
  float* out = (float*)d_out;

  hipMemsetAsync(map, 0xFF, 400000, stream);  // -1
  hipMemsetAsync(z1acc, 0, 1048576, stream);
  hipMemsetAsync(ttl, 0, 16384, stream);
  hipMemsetAsync(acc2, 0, 25600000, stream);
  hipMemsetAsync(out, 0, sizeof(float), stream);

  build_map_kernel<<<16, 256, 0, stream>>>(nu, ni, map);
  spmm_flagged_kernel<<<(nE1 + 3) / 4, 256, 0, stream>>>(rows1, cols1, vals1, ue, ie, map, z1acc, nE1);
  spmm_full_kernel<<<(nE2 + 3) / 4, 256, 0, stream>>>(rows2, cols2, vals2, ue, ie, acc2, nE2);
  normalize2_kernel<<<(N_NODES + 3) / 4, 256, 0, stream>>>(ue, ie, acc2, zallb);
  gather1_kernel<<<SLOTS / 4, 256, 0, stream>>>(ue, ie, nu, ni, map, z1acc, acc2, z1b, out);
  ttl_mfma_kernel<<<64 * STRIPS, 256, 0, stream>>>(z1b, zallb, ttl);
  final_kernel<<<16, 256, 0, stream>>>(ttl, out);
}

// Round 3
// 817.568 us; speedup vs baseline: 13.6843x; 1.2679x over previous
//
#include <hip/hip_runtime.h>
#include <hip/hip_bf16.h>
#include <math.h>

#define N_USERS 50000
#define N_ITEMS 50000
#define N_NODES 100000
#define DIM 64
#define BATCH 2048
#define SLOTS 4096

using frag_ab = __attribute__((ext_vector_type(8))) short;  // 8 bf16
using frag_cd = __attribute__((ext_vector_type(4))) float;  // 4 fp32

// ---------------- helpers ----------------

__device__ __forceinline__ float wave_reduce_sum(float v) {
#pragma unroll
  for (int off = 32; off > 0; off >>= 1)
    v += __shfl_xor(v, off, 64);
  return v;
}

__device__ __forceinline__ int wave_reduce_sum_i(int v) {
#pragma unroll
  for (int off = 32; off > 0; off >>= 1)
    v += __shfl_xor(v, off, 64);
  return v;
}

__device__ __forceinline__ int wave_incl_scan_i(int v, int lane) {
#pragma unroll
  for (int off = 1; off < 64; off <<= 1) {
    int t = __shfl_up(v, off, 64);
    if (lane >= off) v += t;
  }
  return v;
}

__device__ __forceinline__ const float* ego_row(const float* ue, const float* ie, int n) {
  return (n < N_USERS) ? (ue + (size_t)n * DIM) : (ie + (size_t)(n - N_USERS) * DIM);
}

__device__ __forceinline__ ushort f2bf(float x) {
  __hip_bfloat16 h = __float2bfloat16(x);
  return *(ushort*)&h;
}

__device__ __forceinline__ float bf2f(ushort u) {
  return __uint_as_float(((unsigned)u) << 16);
}

// ---------------- small setup kernels ----------------

__global__ void build_map_kernel(const int* __restrict__ nu, const int* __restrict__ ni,
                                 int* __restrict__ map) {
  int s = blockIdx.x * blockDim.x + threadIdx.x;
  if (s >= SLOTS) return;
  int n = (s < BATCH) ? nu[s] : (N_USERS + ni[s - BATCH]);
  map[n] = s;
}

// ego -> bf16 (concatenated node-major table xb[100000][64])
__global__ void ego2bf_kernel(const float* __restrict__ ue, const float* __restrict__ ie,
                              ushort* __restrict__ xb) {
  int t = blockIdx.x * blockDim.x + threadIdx.x;  // index of float4 group
  const int TOT = N_NODES * DIM / 4;
  if (t >= TOT) return;
  const int UH = N_USERS * DIM / 4;
  float4 f = (t < UH) ? ((const float4*)ue)[t] : ((const float4*)ie)[t - UH];
  ushort4 o;
  o.x = f2bf(f.x); o.y = f2bf(f.y); o.z = f2bf(f.z); o.w = f2bf(f.w);
  ((ushort4*)xb)[t] = o;
}

// ---------------- CSR build for graph 2 ----------------

__global__ void hist_kernel(const int* __restrict__ rows, int* __restrict__ deg, int nE) {
  int e = blockIdx.x * blockDim.x + threadIdx.x;
  if (e >= nE) return;
  atomicAdd(&deg[rows[e]], 1);
}

// per-1024-chunk sums
__global__ void scan_p1_kernel(const int* __restrict__ deg, int* __restrict__ bsum) {
  int b = blockIdx.x, t = threadIdx.x;
  int lane = t & 63, wave = t >> 6;
  int base = b * 1024 + t * 4;
  int s = 0;
#pragma unroll
  for (int k = 0; k < 4; k++) {
    int i = base + k;
    if (i < N_NODES) s += deg[i];
  }
  s = wave_reduce_sum_i(s);
  __shared__ int ws[4];
  if (lane == 0) ws[wave] = s;
  __syncthreads();
  if (t == 0) bsum[b] = ws[0] + ws[1] + ws[2] + ws[3];
}

// exclusive scan of the 98 chunk sums (single wave)
__global__ void scan_p2_kernel(int* __restrict__ bsum, int nchunks) {
  int lane = threadIdx.x;
  int v0 = (lane < nchunks) ? bsum[lane] : 0;
  int v1 = (64 + lane < nchunks) ? bsum[64 + lane] : 0;
  int i0 = wave_incl_scan_i(v0, lane);
  int tot0 = __shfl(i0, 63, 64);
  int i1 = wave_incl_scan_i(v1, lane);
  int e0 = i0 - v0;
  int e1 = tot0 + i1 - v1;
  if (lane < nchunks) bsum[lane] = e0;
  if (64 + lane < nchunks) bsum[64 + lane] = e1;
}

// block-level exclusive scan + chunk offset -> rowptr, cursor
__global__ void scan_p3_kernel(const int* __restrict__ deg, const int* __restrict__ bsum,
                               int* __restrict__ rowptr, int* __restrict__ cursor) {
  int b = blockIdx.x, t = threadIdx.x;
  int lane = t & 63, wave = t >> 6;
  int base = b * 1024 + t * 4;
  int d[4];
#pragma unroll
  for (int k = 0; k < 4; k++) {
    int i = base + k;
    d[k] = (i < N_NODES) ? deg[i] : 0;
  }
  int tsum = d[0] + d[1] + d[2] + d[3];
  int incl = wave_incl_scan_i(tsum, lane);
  __shared__ int wtot[4];
  if (lane == 63) wtot[wave] = incl;
  __syncthreads();
  int woff = 0;
  for (int w = 0; w < wave; w++) woff += wtot[w];
  int run = bsum[b] + woff + incl - tsum;
#pragma unroll
  for (int k = 0; k < 4; k++) {
    int i = base + k;
    if (i < N_NODES) {
      rowptr[i] = run;
      cursor[i] = run;
      if (i == N_NODES - 1) rowptr[N_NODES] = run + d[k];
    }
    run += d[k];
  }
}

__global__ void scatter_kernel(const int* __restrict__ rows, const int* __restrict__ cols,
                               const float* __restrict__ vals, int* __restrict__ cursor,
                               int2* __restrict__ pack, int nE) {
  int e = blockIdx.x * blockDim.x + threadIdx.x;
  if (e >= nE) return;
  int r = rows[e];
  int pos = atomicAdd(&cursor[r], 1);
  pack[pos] = make_int2(cols[e], __float_as_int(vals[e]));
}

// gather SpMM (fp32 acc, bf16 x) + 0.5*(ego+.) + l2norm -> zallb. One wave/node.
__global__ void gather_norm_kernel(const int* __restrict__ rowptr, const int2* __restrict__ pack,
                                   const ushort* __restrict__ xb, const float* __restrict__ ue,
                                   const float* __restrict__ ie, ushort* __restrict__ zallb) {
  int n = blockIdx.x * 4 + (threadIdx.x >> 6);
  if (n >= N_NODES) return;
  int lane = threadIdx.x & 63;
  int k = rowptr[n], kend = rowptr[n + 1];
  float acc = 0.f;
  for (; k + 2 <= kend; k += 2) {
    int2 p0 = pack[k];
    int2 p1 = pack[k + 1];
    float x0 = bf2f(xb[(size_t)p0.x * DIM + lane]);
    float x1 = bf2f(xb[(size_t)p1.x * DIM + lane]);
    acc = fmaf(__int_as_float(p0.y), x0, acc);
    acc = fmaf(__int_as_float(p1.y), x1, acc);
  }
  if (k < kend) {
    int2 p = pack[k];
    acc = fmaf(__int_as_float(p.y), bf2f(xb[(size_t)p.x * DIM + lane]), acc);
  }
  const float* eg = ego_row(ue, ie, n);
  float v = 0.5f * (eg[lane] + acc);
  float ss = wave_reduce_sum(v * v);
  float z = v / fmaxf(sqrtf(ss), 1e-12f);
  zallb[(size_t)n * DIM + lane] = f2bf(z);
}

// ---------------- graph 1 (flagged rows only) ----------------

__global__ void spmm_flagged_kernel(const int* __restrict__ rows, const int* __restrict__ cols,
                                    const float* __restrict__ vals, const float* __restrict__ ue,
                                    const float* __restrict__ ie, const int* __restrict__ map,
                                    float* __restrict__ z1acc, int nE) {
  int e = blockIdx.x * 4 + (threadIdx.x >> 6);
  if (e >= nE) return;
  int r = rows[e];
  int s = map[r];
  if (s < 0) return;  // wave-uniform branch
  int lane = threadIdx.x & 63;
  int c = cols[e];
  float v = vals[e];
  const float* x = ego_row(ue, ie, c);
  unsafeAtomicAdd(&z1acc[(size_t)s * DIM + lane], v * x[lane]);
}

// z1 normalize (fp32) -> bf16; pos term out -= dot(z1, z2) with z2 from zallb.
__global__ void gather1_kernel(const float* __restrict__ ue, const float* __restrict__ ie,
                               const int* __restrict__ nu, const int* __restrict__ ni,
                               const int* __restrict__ map, const float* __restrict__ z1acc,
                               const ushort* __restrict__ zallb, ushort* __restrict__ z1b,
                               float* __restrict__ out) {
  int s = blockIdx.x * 4 + (threadIdx.x >> 6);
  if (s >= SLOTS) return;
  int lane = threadIdx.x & 63;
  int n = (s < BATCH) ? nu[s] : (N_USERS + ni[s - BATCH]);
  int fs = map[n];
  const float* e = ego_row(ue, ie, n);
  float v = 0.5f * (e[lane] + z1acc[(size_t)fs * DIM + lane]);
  float ss = wave_reduce_sum(v * v);
  float z = v / fmaxf(sqrtf(ss), 1e-12f);
  z1b[(size_t)s * DIM + lane] = f2bf(z);
  float dp = wave_reduce_sum(z * bf2f(zallb[(size_t)n * DIM + lane]));
  if (lane == 0) atomicAdd(out, -dp);
}

// ---------------- ttl (bf16 MFMA) ----------------
// Wave tile: M=32 z1 rows x 16 j per chunk, K=64 -> 4 MFMAs/chunk.
// Block = 4 waves = 128 rows, one strip of 25 chunks (400 j). Grid 32x125.
#define TTL_STRIPS 125
#define TTL_CHUNKS 25
__global__ __launch_bounds__(256) void ttl_mfma_kernel(const ushort* __restrict__ z1b,
                                                       const ushort* __restrict__ zallb,
                                                       float* __restrict__ ttl) {
  int rb = blockIdx.x / TTL_STRIPS;
  int strip = blockIdx.x % TTL_STRIPS;
  int wave = threadIdx.x >> 6;
  int lane = threadIdx.x & 63;
  int r0 = rb * 128 + wave * 32;
  int side = r0 >> 11;  // rows 0..2047 users, 2048..4095 items
  const ushort* zs = zallb + (size_t)side * N_USERS * DIM;

  int m = lane & 15, q = lane >> 4;
  const ushort* ar0 = z1b + (size_t)(r0 + m) * DIM + q * 8;
  frag_ab a00 = *(const frag_ab*)ar0;
  frag_ab a01 = *(const frag_ab*)(ar0 + 32);
  const ushort* ar1 = ar0 + 16 * DIM;
  frag_ab a10 = *(const frag_ab*)ar1;
  frag_ab a11 = *(const frag_ab*)(ar1 + 32);

  int j0 = strip * (TTL_CHUNKS * 16);
  const ushort* bp = zs + (size_t)(j0 + m) * DIM + q * 8;

  // depth-2 register pipeline on B
  frag_ab b0c = *(const frag_ab*)bp;
  frag_ab b1c = *(const frag_ab*)(bp + 32);
  const ushort* bp1 = bp + 16 * DIM;
  frag_ab b0n = *(const frag_ab*)bp1;
  frag_ab b1n = *(const frag_ab*)(bp1 + 32);

  float racc[8] = {0.f, 0.f, 0.f, 0.f, 0.f, 0.f, 0.f, 0.f};

  for (int c = 0; c < TTL_CHUNKS; c++) {
    frag_ab b0f = b0c, b1f = b1c;
    if (c + 2 < TTL_CHUNKS) {
      const ushort* bp2 = bp + 2 * 16 * DIM;
      b0f = *(const frag_ab*)bp2;
      b1f = *(const frag_ab*)(bp2 + 32);
    }
    frag_cd acc0 = {}, acc1 = {};
    acc0 = __builtin_amdgcn_mfma_f32_16x16x32_bf16(a00, b0c, acc0, 0, 0, 0);
    acc0 = __builtin_amdgcn_mfma_f32_16x16x32_bf16(a01, b1c, acc0, 0, 0, 0);
    acc1 = __builtin_amdgcn_mfma_f32_16x16x32_bf16(a10, b0c, acc1, 0, 0, 0);
    acc1 = __builtin_amdgcn_mfma_f32_16x16x32_bf16(a11, b1c, acc1, 0, 0, 0);
#pragma unroll
    for (int r = 0; r < 4; r++) {
      racc[r] += __expf(2.f * acc0[r]);
      racc[4 + r] += __expf(2.f * acc1[r]);
    }
    b0c = b0n; b1c = b1n;
    b0n = b0f; b1n = b1f;
    bp += 16 * DIM;
  }

  // C layout: col(=zall j) = lane&15, row(=z1 row) = q*4+reg. Reduce over j lanes.
#pragma unroll
  for (int h = 0; h < 2; h++) {
#pragma unroll
    for (int r = 0; r < 4; r++) {
      float v = racc[h * 4 + r];
      v += __shfl_xor(v, 1, 64);
      v += __shfl_xor(v, 2, 64);
      v += __shfl_xor(v, 4, 64);
      v += __shfl_xor(v, 8, 64);
      if (m == 0) atomicAdd(&ttl[r0 + h * 16 + q * 4 + r], v);
    }
  }
}

// out += 0.5 * sum_i log(ttl[i])
__global__ void final_kernel(const float* __restrict__ ttl, float* __restrict__ out) {
  int t = blockIdx.x * blockDim.x + threadIdx.x;
  float v = (t < SLOTS) ? 0.5f * logf(ttl[t]) : 0.f;
  v = wave_reduce_sum(v);
  if ((threadIdx.x & 63) == 0) atomicAdd(out, v);
}

// ---------------- launch ----------------

extern "C" void kernel_launch(void* const* d_in, const int* in_sizes, int n_in,
                              void* d_out, int out_size, void* d_ws, size_t ws_size,
                              hipStream_t stream) {
  const float* ue = (const float*)d_in[0];
  const float* ie = (const float*)d_in[1];
  const int* rows1 = (const int*)d_in[2];
  const int* cols1 = (const int*)d_in[3];
  const float* vals1 = (const float*)d_in[4];
  const int* rows2 = (const int*)d_in[5];
  const int* cols2 = (const int*)d_in[6];
  const float* vals2 = (const float*)d_in[7];
  const int* nu = (const int*)d_in[8];
  const int* ni = (const int*)d_in[9];
  int nE1 = in_sizes[2], nE2 = in_sizes[5];

  // workspace carve-out (256B aligned), total ~44.8 MB
  char* ws = (char*)d_ws;
  size_t o = 0;
  auto carve = [&](size_t bytes) {
    char* p = ws + o;
    o += (bytes + 255) & ~(size_t)255;
    return p;
  };
  int* map = (int*)carve(N_NODES * 4);
  float* z1acc = (float*)carve((size_t)SLOTS * DIM * 4);
  float* ttl = (float*)carve(SLOTS * 4);
  ushort* zallb = (ushort*)carve((size_t)N_NODES * DIM * 2);
  ushort* z1b = (ushort*)carve((size_t)SLOTS * DIM * 2);
  ushort* xb = (ushort*)carve((size_t)N_NODES * DIM * 2);
  int* deg = (int*)carve(N_NODES * 4);
  int* rowptr = (int*)carve((N_NODES + 1) * 4);
  int* cursor = (int*)carve(N_NODES * 4);
  int* bsum = (int*)carve(128 * 4);
  int2* pack = (int2*)carve((size_t)nE2 * 8);
  float* out = (float*)d_out;

  const int NCHUNKS = (N_NODES + 1023) / 1024;  // 98

  hipMemsetAsync(map, 0xFF, N_NODES * 4, stream);  // -1
  hipMemsetAsync(z1acc, 0, (size_t)SLOTS * DIM * 4, stream);
  hipMemsetAsync(ttl, 0, SLOTS * 4, stream);
  hipMemsetAsync(deg, 0, N_NODES * 4, stream);
  hipMemsetAsync(out, 0, sizeof(float), stream);

  build_map_kernel<<<16, 256, 0, stream>>>(nu, ni, map);
  ego2bf_kernel<<<(N_NODES * DIM / 4 + 255) / 256, 256, 0, stream>>>(ue, ie, xb);
  hist_kernel<<<(nE2 + 255) / 256, 256, 0, stream>>>(rows2, deg, nE2);
  scan_p1_kernel<<<NCHUNKS, 256, 0, stream>>>(deg, bsum);
  scan_p2_kernel<<<1, 64, 0, stream>>>(bsum, NCHUNKS);
  scan_p3_kernel<<<NCHUNKS, 256, 0, stream>>>(deg, bsum, rowptr, cursor);
  scatter_kernel<<<(nE2 + 255) / 256, 256, 0, stream>>>(rows2, cols2, vals2, cursor, pack, nE2);
  gather_norm_kernel<<<(N_NODES + 3) / 4, 256, 0, stream>>>(rowptr, pack, xb, ue, ie, zallb);
  spmm_flagged_kernel<<<(nE1 + 3) / 4, 256, 0, stream>>>(rows1, cols1, vals1, ue, ie, map, z1acc, nE1);
  gather1_kernel<<<SLOTS / 4, 256, 0, stream>>>(ue, ie, nu, ni, map, z1acc, zallb, z1b, out);
  ttl_mfma_kernel<<<32 * TTL_STRIPS, 256, 0, stream>>>(z1b, zallb, ttl);
  final_kernel<<<16, 256, 0, stream>>>(ttl, out);
}